// Round 8
// baseline (1211.435 us; speedup 1.0000x reference)
//
#include <hip/hip_runtime.h>

// DecoderWithAttention: B=16, T=32, F=8, S_ENC=256, H=512, L=2.
// R8 = R7 structure with two fixes:
//  - L_H1OWN store index now matches read layout (bb*2 + pp). R7 stored at
//    pp*8 + bb -> GRU1 used wrong h1_old -> absmax 2.03.
//  - Wide uncached staging loads now carry s_waitcnt vmcnt(0) INSIDE one asm
//    block with early-clobber outputs (compiler cannot touch results before
//    data lands). hidP staged via all-thread dwordx2.
// Structure recap: 2 halves x 128 row-slice blocks x 256 thr; 3 barriers/step
// (B | D | E); Whh0@h0, Whh1@h1 precomputed in B; hidP(t+1) accumulated in E
// via fp32 atomicAdd outer-product (own 4 h1new rows x LDS-pinned whidT).

namespace {
constexpr int kB = 16, kT = 32, kF = 8, kS = 256, kH = 512;
constexpr int NBLK = 256, NTHR = 256;

constexpr int OFF_AEH   = 1024;
constexpr int OFF_WHIDT = OFF_AEH + 131072;
constexpr int OFF_WIH0  = OFF_WHIDT + 131072;
constexpr int OFF_WHH0  = OFF_WIH0 + 399360;
constexpr int OFF_WIH1  = OFF_WHH0 + 393216;
constexpr int OFF_WHH1  = OFF_WIH1 + 393216;
constexpr int OFF_ENCH  = OFF_WHH1 + 393216;
constexpr int OFF_ENCP  = OFF_ENCH + 1048576;
constexpr int OFF_HIDPA = OFF_ENCP + 1048576;   // [2][16][512] f32
constexpr int OFF_WEIA  = OFF_HIDPA + 16384;    // [2][16][512] f32
constexpr int OFF_LACC  = OFF_WEIA + 16384;     // [2][16]
constexpr int OFF_OUTB  = OFF_LACC + 32;        // [2][16][8]
constexpr int OFF_H0C   = OFF_OUTB + 256;       // [2][16][256] u32
constexpr int OFF_H1C   = OFF_H0C + 8192;       // [2][16][256] u32
constexpr int OFF_XINC  = OFF_H1C + 8192;       // [2][16][8]
constexpr int OFF_OUTP  = OFF_XINC + 256;       // [16][128][8]

constexpr int L_WIH0 = 0;
constexpr int L_WHH0 = 3168;
constexpr int L_WHIDT= 6240;
constexpr int L_VW   = 7264;
constexpr int L_BIH0 = 7776, L_BHH0 = 7788, L_BIH1 = 7800, L_BHH1 = 7812;
constexpr int L_OOW  = 7824;
constexpr int L_S1   = 7856;     // u32 [8][264]
constexpr int L_S0   = 9968;     // u32 [8][264]
constexpr int L_HIDP = 12080;    // f32 [512]
constexpr int L_ES   = 12592;
constexpr int L_AH0  = 12608;
constexpr int L_AH1  = 12704;
constexpr int L_AX   = 12800;
constexpr int L_HS   = 12896;
constexpr int L_XINL = 12928;
constexpr int L_INV  = 12936;
constexpr int L_H1OWN= 12944;
constexpr int LDS_FLOATS = 12960;
}  // namespace

typedef _Float16 h2 __attribute__((ext_vector_type(2)));
typedef unsigned u2v __attribute__((ext_vector_type(2)));
union U32H { unsigned u; h2 h; };
union U4F4 { uint4 u; float4 f; };

__device__ __forceinline__ float dot2(unsigned a, unsigned b, float acc) {
    U32H ua, ub; ua.u = a; ub.u = b;
#if __has_builtin(__builtin_amdgcn_fdot2)
    return __builtin_amdgcn_fdot2(ua.h, ub.h, acc, false);
#else
    return acc + (float)ua.h.x * (float)ub.h.x + (float)ua.h.y * (float)ub.h.y;
#endif
}
__device__ __forceinline__ unsigned packh2(float a, float b) {
    U32H u; u.h = h2{(_Float16)a, (_Float16)b}; return u.u;
}
__device__ __forceinline__ float fsig(float x) { return 1.0f / (1.0f + __expf(-x)); }
__device__ __forceinline__ float ftanhf(float x) {
    float e = __expf(2.0f * x);
    return 1.0f - 2.0f / (e + 1.0f);
}
__device__ __forceinline__ float cload(const float* p) {
    return __hip_atomic_load(p, __ATOMIC_RELAXED, __HIP_MEMORY_SCOPE_SYSTEM);
}
__device__ __forceinline__ void cstore(float* p, float v) {
    __hip_atomic_store(p, v, __ATOMIC_RELAXED, __HIP_MEMORY_SCOPE_SYSTEM);
}
__device__ __forceinline__ unsigned ucload(const unsigned* p) {
    return __hip_atomic_load(p, __ATOMIC_RELAXED, __HIP_MEMORY_SCOPE_SYSTEM);
}
__device__ __forceinline__ void ucstore(unsigned* p, unsigned v) {
    __hip_atomic_store(p, v, __ATOMIC_RELAXED, __HIP_MEMORY_SCOPE_SYSTEM);
}

// Batched uncached staging loads. s_waitcnt vmcnt(0) INSIDE the asm block +
// early-clobber outputs: results are valid when the block completes, and the
// compiler cannot copy/spill result registers before the data lands.
__device__ __forceinline__ void ucl_b(uint4& a0, uint4& a1, uint4& b0, uint4& b1, u2v& c,
                                      const void* pa0, const void* pa1,
                                      const void* pb0, const void* pb1, const void* pc) {
    asm volatile(
        "global_load_dwordx4 %0, %5, off sc0 sc1\n\t"
        "global_load_dwordx4 %1, %6, off sc0 sc1\n\t"
        "global_load_dwordx4 %2, %7, off sc0 sc1\n\t"
        "global_load_dwordx4 %3, %8, off sc0 sc1\n\t"
        "global_load_dwordx2 %4, %9, off sc0 sc1\n\t"
        "s_waitcnt vmcnt(0)"
        : "=&v"(a0), "=&v"(a1), "=&v"(b0), "=&v"(b1), "=&v"(c)
        : "v"(pa0), "v"(pa1), "v"(pb0), "v"(pb1), "v"(pc)
        : "memory");
}
__device__ __forceinline__ void ucl_d(uint4& w0, uint4& w1, uint4& w2, uint4& w3,
                                      const void* p0, const void* p1,
                                      const void* p2, const void* p3) {
    asm volatile(
        "global_load_dwordx4 %0, %4, off sc0 sc1\n\t"
        "global_load_dwordx4 %1, %5, off sc0 sc1\n\t"
        "global_load_dwordx4 %2, %6, off sc0 sc1\n\t"
        "global_load_dwordx4 %3, %7, off sc0 sc1\n\t"
        "s_waitcnt vmcnt(0)"
        : "=&v"(w0), "=&v"(w1), "=&v"(w2), "=&v"(w3)
        : "v"(p0), "v"(p1), "v"(p2), "v"(p3)
        : "memory");
}
__device__ __forceinline__ void ucl_e(uint4& a0, uint4& a1, const void* p0, const void* p1) {
    asm volatile(
        "global_load_dwordx4 %0, %2, off sc0 sc1\n\t"
        "global_load_dwordx4 %1, %3, off sc0 sc1\n\t"
        "s_waitcnt vmcnt(0)"
        : "=&v"(a0), "=&v"(a1)
        : "v"(p0), "v"(p1)
        : "memory");
}

__device__ __forceinline__ void bar_sync(unsigned* cnt, unsigned target) {
    __syncthreads();
    if (threadIdx.x == 0) {
        __builtin_amdgcn_fence(__ATOMIC_RELEASE, "workgroup");
        __builtin_amdgcn_s_waitcnt(0);
        __hip_atomic_fetch_add(cnt, 1u, __ATOMIC_RELAXED, __HIP_MEMORY_SCOPE_SYSTEM);
        while (__hip_atomic_load(cnt, __ATOMIC_RELAXED, __HIP_MEMORY_SCOPE_SYSTEM) < target)
            __builtin_amdgcn_s_sleep(1);
        __builtin_amdgcn_fence(__ATOMIC_ACQUIRE, "workgroup");
    }
    __syncthreads();
}
__device__ __forceinline__ void bar_sync_flush(unsigned* cnt, unsigned target) {
    __syncthreads();
    if (threadIdx.x == 0) {
        __builtin_amdgcn_fence(__ATOMIC_RELEASE, "agent");
        __hip_atomic_fetch_add(cnt, 1u, __ATOMIC_RELAXED, __HIP_MEMORY_SCOPE_SYSTEM);
        while (__hip_atomic_load(cnt, __ATOMIC_RELAXED, __HIP_MEMORY_SCOPE_SYSTEM) < target)
            __builtin_amdgcn_s_sleep(8);
        __builtin_amdgcn_fence(__ATOMIC_ACQUIRE, "agent");
    }
    __syncthreads();
}

__global__ __launch_bounds__(NTHR) void decoder_kernel(
    const float* __restrict__ target, const float* __restrict__ hidden0,
    const float* __restrict__ enc, const float* __restrict__ attn_W,
    const float* __restrict__ attn_b, const float* __restrict__ v_w,
    const float* __restrict__ Wih0, const float* __restrict__ Whh0,
    const float* __restrict__ bih0, const float* __restrict__ bhh0,
    const float* __restrict__ Wih1, const float* __restrict__ Whh1,
    const float* __restrict__ bih1, const float* __restrict__ bhh1,
    const float* __restrict__ outW, const float* __restrict__ outBias,
    float* __restrict__ out, float* __restrict__ ws) {
    const int tid = threadIdx.x, bid = blockIdx.x;
    const int half = bid >> 7, j = bid & 127;
    const int bloc = j >> 4, sgrp = j & 15;
    const int b_att = half * 8 + bloc;
    unsigned* halfCnt = (unsigned*)ws + 32 * half;
    unsigned* gridCnt = (unsigned*)ws + 64;
    unsigned bars = 0;

    unsigned* aehU   = (unsigned*)(ws + OFF_AEH);
    unsigned* whidTU = (unsigned*)(ws + OFF_WHIDT);
    unsigned* wih0U  = (unsigned*)(ws + OFF_WIH0);
    unsigned* whh0U  = (unsigned*)(ws + OFF_WHH0);
    unsigned* wih1U  = (unsigned*)(ws + OFF_WIH1);
    unsigned* whh1U  = (unsigned*)(ws + OFF_WHH1);
    unsigned* encU   = (unsigned*)(ws + OFF_ENCH);
    unsigned* encpU  = (unsigned*)(ws + OFF_ENCP);
    float* hidPA = ws + OFF_HIDPA;
    float* weiA  = ws + OFF_WEIA;
    float* lacc  = ws + OFF_LACC;
    float* outBs = ws + OFF_OUTB;
    unsigned* h0cU = (unsigned*)(ws + OFF_H0C);
    unsigned* h1cU = (unsigned*)(ws + OFF_H1C);
    float* xinC = ws + OFF_XINC;
    float* outP = ws + OFF_OUTP;

    __shared__ __align__(16) float lds[LDS_FLOATS];
    unsigned* ldsU = (unsigned*)lds;
    const int gtid = bid * NTHR + tid;

    // ===================== P1: pack + init =====================
    for (int i = gtid; i < 131072; i += NBLK * NTHR) {
        const int k = i >> 8, p = i & 255;
        aehU[i]   = packh2(attn_W[k * 1024 + 512 + 2 * p], attn_W[k * 1024 + 513 + 2 * p]);
        whidTU[i] = packh2(attn_W[(2 * p) * 1024 + k], attn_W[(2 * p + 1) * 1024 + k]);
    }
    for (int i = gtid; i < 399360; i += NBLK * NTHR)
        wih0U[i] = packh2(Wih0[2 * i], Wih0[2 * i + 1]);
    for (int i = gtid; i < 393216; i += NBLK * NTHR) {
        whh0U[i] = packh2(Whh0[2 * i], Whh0[2 * i + 1]);
        wih1U[i] = packh2(Wih1[2 * i], Wih1[2 * i + 1]);
        whh1U[i] = packh2(Whh1[2 * i], Whh1[2 * i + 1]);
    }
    for (int i = gtid; i < 1048576; i += NBLK * NTHR)
        encU[i] = packh2(enc[2 * i], enc[2 * i + 1]);
    if (gtid < 4096) {
        const int bb = gtid >> 8, p = gtid & 255;
        h0cU[gtid] = packh2(hidden0[bb * 512 + 2 * p], hidden0[bb * 512 + 2 * p + 1]);
        h1cU[gtid] = packh2(hidden0[8192 + bb * 512 + 2 * p], hidden0[8192 + bb * 512 + 2 * p + 1]);
    }
    if (gtid < 128) {
        const int bb = gtid >> 3, f = gtid & 7;
        xinC[gtid] = target[bb * 256 + f];
    }
    for (int i = gtid; i < 33056; i += NBLK * NTHR)
        ws[OFF_HIDPA + i] = 0.f;
    bar_sync_flush(gridCnt, NBLK);

    // ===================== P2: enc_proj =====================
    {
        for (int i = 0; i < 16; ++i) {
            const int idx = tid + i * 256;
            const int s = idx >> 8, p = idx & 255;
            ldsU[idx] = encU[(b_att * 256 + sgrp * 16 + s) * 256 + p];
        }
        __syncthreads();
        float a0[16], a1[16];
        const float bb0 = attn_b[2 * tid], bb1 = attn_b[2 * tid + 1];
#pragma unroll
        for (int s = 0; s < 16; ++s) { a0[s] = bb0; a1[s] = bb1; }
        const unsigned* w0 = &aehU[(2 * tid) * 256];
        const unsigned* w1 = &aehU[(2 * tid + 1) * 256];
        for (int p = 0; p < 256; ++p) {
            const unsigned ww0 = w0[p], ww1 = w1[p];
#pragma unroll
            for (int s = 0; s < 16; ++s) {
                const unsigned e = ldsU[s * 256 + p];
                a0[s] = dot2(e, ww0, a0[s]);
                a1[s] = dot2(e, ww1, a1[s]);
            }
        }
        for (int s = 0; s < 16; ++s)
            encpU[(b_att * 256 + sgrp * 16 + s) * 256 + tid] = packh2(a0[s], a1[s]);
        __syncthreads();
    }

    // ===================== P3: pin weights in LDS =====================
    for (int gh = 0; gh < 12; ++gh) {
        const int grow = (gh >> 2) * 512 + j * 4 + (gh & 3);
        for (int p = tid; p < 260; p += 256) ldsU[L_WIH0 + gh * 264 + p] = wih0U[grow * 260 + p];
        if (tid < 4) ldsU[L_WIH0 + gh * 264 + 260 + tid] = 0u;
        ldsU[L_WHH0 + gh * 256 + tid] = whh0U[grow * 256 + tid];
    }
    for (int kk = 0; kk < 4; ++kk)
        ldsU[L_WHIDT + kk * 256 + tid] = whidTU[(j * 4 + kk) * 256 + tid];
    if (tid < 12) {
        const int grow = (tid >> 2) * 512 + j * 4 + (tid & 3);
        lds[L_BIH0 + tid] = bih0[grow]; lds[L_BHH0 + tid] = bhh0[grow];
        lds[L_BIH1 + tid] = bih1[grow]; lds[L_BHH1 + tid] = bhh1[grow];
    }
    if (tid < 32) lds[L_OOW + tid] = outW[(tid >> 2) * 1032 + j * 4 + (tid & 3)];
    lds[L_VW + tid] = v_w[tid];
    lds[L_VW + 256 + tid] = v_w[256 + tid];
    __syncthreads();

    // ===================== P4: initial hidP =====================
    if (tid < 16)  // FIXED layout: bb*2 + pp (read side uses bb*2 + (hr>>1))
        ldsU[L_H1OWN + (tid & 7) * 2 + (tid >> 3)] =
            h1cU[(half * 8 + (tid & 7)) * 256 + j * 2 + (tid >> 3)];
    __syncthreads();
    if (tid < 32) {
        const int hr = tid >> 3, bb = tid & 7;
        U32H u; u.u = ldsU[L_H1OWN + bb * 2 + (hr >> 1)];
        lds[L_HS + hr * 8 + bb] = (hr & 1) ? (float)u.h.y : (float)u.h.x;
    }
    __syncthreads();
    {
        float wlo[4], whi[4];
#pragma unroll
        for (int k = 0; k < 4; ++k) {
            U32H u; u.u = ldsU[L_WHIDT + k * 256 + tid];
            wlo[k] = (float)u.h.x; whi[k] = (float)u.h.y;
        }
#pragma unroll
        for (int bb = 0; bb < 8; ++bb) {
            float p0 = 0.f, p1 = 0.f;
#pragma unroll
            for (int k = 0; k < 4; ++k) {
                const float hv = lds[L_HS + k * 8 + bb];
                p0 += hv * wlo[k]; p1 += hv * whi[k];
            }
            atomicAdd(&hidPA[(half * 8 + bb) * 512 + 2 * tid], p0);
            atomicAdd(&hidPA[(half * 8 + bb) * 512 + 2 * tid + 1], p1);
        }
    }
    bar_sync(halfCnt, 128 * (++bars));

    // ===================== main loop: B | D | E =====================
    for (int t = 0; t < kT; ++t) {
        const int par = t & 1;

        // ---- B: finalize out[t-1]; stage h1/h0/hidP; energy->weiA; AH0/AH1 ----
        {
            if (t > 0 && sgrp == 15 && tid < 64) {
                const int f = tid >> 3, sub = tid & 7;
                float acc = 0.f;
                for (int i = 0; i < 16; ++i)
                    acc += cload(&outP[(b_att * 128 + sub * 16 + i) * 8 + f]);
                acc += __shfl_down(acc, 4, 8); acc += __shfl_down(acc, 2, 8); acc += __shfl_down(acc, 1, 8);
                if (sub == 0) {
                    acc += cload(&outBs[(par ^ 1) * 128 + b_att * 8 + f]);
                    const float o = fmaxf(acc, 0.f);
                    out[b_att * 256 + (t - 1) * 8 + f] = o;
                    cstore(&xinC[par * 128 + b_att * 8 + f], o);
                }
            }
            uint4 a0, a1, b0, b1; u2v c;
            ucl_b(a0, a1, b0, b1, c,
                  &h1cU[par * 4096 + half * 2048 + tid * 4],
                  &h1cU[par * 4096 + half * 2048 + (tid + 256) * 4],
                  &h0cU[par * 4096 + half * 2048 + tid * 4],
                  &h0cU[par * 4096 + half * 2048 + (tid + 256) * 4],
                  &hidPA[par * 8192 + b_att * 512 + tid * 2]);
            {
                const int bb0i = tid >> 6, p40 = tid & 63;
                const int bb1i = (tid + 256) >> 6, p41 = (tid + 256) & 63;
                *(uint4*)&ldsU[L_S1 + bb0i * 264 + p40 * 4] = a0;
                *(uint4*)&ldsU[L_S1 + bb1i * 264 + p41 * 4] = a1;
                *(uint4*)&ldsU[L_S0 + bb0i * 264 + p40 * 4] = b0;
                *(uint4*)&ldsU[L_S0 + bb1i * 264 + p41 * 4] = b1;
                lds[L_HIDP + tid * 2] = __uint_as_float(c.x);
                lds[L_HIDP + tid * 2 + 1] = __uint_as_float(c.y);
            }
            __syncthreads();
            {
                const int sloc = tid >> 4, sub = tid & 15;
                const unsigned* ep = &encpU[(b_att * 256 + sgrp * 16 + sloc) * 256];
                float acc = 0.f;
#pragma unroll 4
                for (int k2 = 0; k2 < 16; ++k2) {
                    const int p = k2 * 16 + sub;
                    U32H u; u.u = ep[p];
                    acc += lds[L_VW + 2 * p] * ftanhf((float)u.h.x + lds[L_HIDP + 2 * p]);
                    acc += lds[L_VW + 2 * p + 1] * ftanhf((float)u.h.y + lds[L_HIDP + 2 * p + 1]);
                }
                acc += __shfl_down(acc, 8, 16); acc += __shfl_down(acc, 4, 16);
                acc += __shfl_down(acc, 2, 16); acc += __shfl_down(acc, 1, 16);
                if (sub == 0) lds[L_ES + sloc] = __expf(acc);  // |score| small: fp32-safe
            }
            __syncthreads();
            {
                float wp0 = 0.f, wp1 = 0.f;
                const unsigned* er = &encU[(b_att * 256 + sgrp * 16) * 256 + tid];
#pragma unroll
                for (int sl = 0; sl < 16; ++sl) {
                    U32H u; u.u = er[sl * 256];
                    const float es = lds[L_ES + sl];
                    wp0 += es * (float)u.h.x; wp1 += es * (float)u.h.y;
                }
                atomicAdd(&weiA[par * 8192 + b_att * 512 + 2 * tid], wp0);
                atomicAdd(&weiA[par * 8192 + b_att * 512 + 2 * tid + 1], wp1);
                if (tid == 0) {
                    float l = 0.f;
#pragma unroll
                    for (int i = 0; i < 16; ++i) l += lds[L_ES + i];
                    atomicAdd(&lacc[par * 16 + b_att], l);
                }
            }
            if (tid < 192) {
                const int u = tid >> 1, sub = tid & 1;
                const int bb = u & 7, gh = u >> 3;
                const uint4* wh = (const uint4*)&ldsU[L_WHH0 + gh * 256 + sub * 128];
                const uint4* hp = (const uint4*)&ldsU[L_S0 + bb * 264 + sub * 128];
                float ah = 0.f;
#pragma unroll 8
                for (int k4 = 0; k4 < 32; ++k4) {
                    const uint4 hv = hp[k4], wv = wh[k4];
                    ah = dot2(hv.x, wv.x, ah); ah = dot2(hv.y, wv.y, ah);
                    ah = dot2(hv.z, wv.z, ah); ah = dot2(hv.w, wv.w, ah);
                }
                ah += __shfl_down(ah, 1, 2);
                if (sub == 0) lds[L_AH0 + gh * 8 + bb] = ah + lds[L_BHH0 + gh];
            }
            if (tid < 192) {
                const int u = tid >> 1, sub = tid & 1;
                const int bb = u & 7, gh = u >> 3;
                const int grow = (gh >> 2) * 512 + j * 4 + (gh & 3);
                const uint4* wh = (const uint4*)&whh1U[grow * 256 + sub * 128];
                const uint4* hp = (const uint4*)&ldsU[L_S1 + bb * 264 + sub * 128];
                float ah = 0.f;
#pragma unroll 8
                for (int k4 = 0; k4 < 32; ++k4) {
                    const uint4 hv = hp[k4], wv = wh[k4];
                    ah = dot2(hv.x, wv.x, ah); ah = dot2(hv.y, wv.y, ah);
                    ah = dot2(hv.z, wv.z, ah); ah = dot2(hv.w, wv.w, ah);
                }
                ah += __shfl_down(ah, 1, 2);
                if (sub == 0) lds[L_AH1 + gh * 8 + bb] = ah + lds[L_BHH1 + gh];
            }
        }
        bar_sync(halfCnt, 128 * (++bars));

        // ---- D: normalize wei; GRU0 x-side + gates; outBs; zero hidPA[par] ----
        {
            if (tid < 8) lds[L_INV + tid] = 1.f / cload(&lacc[par * 16 + half * 8 + tid]);
            if (sgrp == 14 && tid >= 8 && tid < 16)
                lds[L_XINL + tid - 8] = cload(&xinC[par * 128 + b_att * 8 + (tid - 8)]);
            if (tid >= 32 && tid < 64) {
                const int bb = (tid - 32) >> 2, q4 = (tid - 32) & 3;
                const float f0 = cload(&xinC[par * 128 + (half * 8 + bb) * 8 + 2 * q4]);
                const float f1 = cload(&xinC[par * 128 + (half * 8 + bb) * 8 + 2 * q4 + 1]);
                ldsU[L_S1 + bb * 264 + q4] = packh2(f0, f1);
                ldsU[L_S1 + bb * 264 + 260 + q4] = 0u;
            }
            uint4 w40, w41, w42, w43;
            ucl_d(w40, w41, w42, w43,
                  &weiA[par * 8192 + half * 4096 + (tid * 4 + 0) * 4],
                  &weiA[par * 8192 + half * 4096 + (tid * 4 + 1) * 4],
                  &weiA[par * 8192 + half * 4096 + (tid * 4 + 2) * 4],
                  &weiA[par * 8192 + half * 4096 + (tid * 4 + 3) * 4]);
            __syncthreads();  // L_INV + xin pairs visible
            {
                uint4 w4[4] = {w40, w41, w42, w43};
#pragma unroll
                for (int i = 0; i < 4; ++i) {
                    const int idx4 = tid * 4 + i;
                    const int bb = idx4 >> 7, q = idx4 & 127;
                    U4F4 cc; cc.u = w4[i];
                    const float inv = lds[L_INV + bb];
                    ldsU[L_S1 + bb * 264 + 4 + 2 * q] = packh2(cc.f.x * inv, cc.f.y * inv);
                    ldsU[L_S1 + bb * 264 + 4 + 2 * q + 1] = packh2(cc.f.z * inv, cc.f.w * inv);
                }
            }
            __syncthreads();
            if (tid < 192) {
                const int u = tid >> 1, sub = tid & 1;
                const int bb = u & 7, gh = u >> 3;
                const uint4* wx = (const uint4*)&ldsU[L_WIH0 + gh * 264 + sub * 132];
                const uint4* xp = (const uint4*)&ldsU[L_S1 + bb * 264 + sub * 132];
                float ax = 0.f;
#pragma unroll 11
                for (int k4 = 0; k4 < 33; ++k4) {
                    const uint4 xv = xp[k4], wv = wx[k4];
                    ax = dot2(xv.x, wv.x, ax); ax = dot2(xv.y, wv.y, ax);
                    ax = dot2(xv.z, wv.z, ax); ax = dot2(xv.w, wv.w, ax);
                }
                ax += __shfl_down(ax, 1, 2);
                if (sub == 0) lds[L_AX + gh * 8 + bb] = ax + lds[L_BIH0 + gh];
            }
            __syncthreads();
            if (tid < 32) {
                const int hr = tid >> 3, bb = tid & 7;
                const float r = fsig(lds[L_AX + hr * 8 + bb] + lds[L_AH0 + hr * 8 + bb]);
                const float z = fsig(lds[L_AX + (4 + hr) * 8 + bb] + lds[L_AH0 + (4 + hr) * 8 + bb]);
                const float n = ftanhf(lds[L_AX + (8 + hr) * 8 + bb] + r * lds[L_AH0 + (8 + hr) * 8 + bb]);
                U32H u; u.u = ldsU[L_S0 + bb * 264 + j * 2 + (hr >> 1)];
                const float hold = (hr & 1) ? (float)u.h.y : (float)u.h.x;
                lds[L_HS + hr * 8 + bb] = (1.f - z) * n + z * hold;
            }
            if (sgrp == 14 && tid >= 64 && tid < 128) {
                const int f = (tid - 64) >> 3, sub2 = tid & 7;
                float acc = 0.f;
                const float* ow = &outW[f * 1032 + 512 + sub2 * 64];
#pragma unroll 8
                for (int p2 = 0; p2 < 32; ++p2) {
                    U32H u; u.u = ldsU[L_S1 + bloc * 264 + 4 + sub2 * 32 + p2];
                    acc += ow[2 * p2] * (float)u.h.x + ow[2 * p2 + 1] * (float)u.h.y;
                }
                acc += __shfl_down(acc, 4, 8); acc += __shfl_down(acc, 2, 8); acc += __shfl_down(acc, 1, 8);
                if (sub2 == 0) {
#pragma unroll
                    for (int ff = 0; ff < 8; ++ff)
                        acc += outW[f * 1032 + 1024 + ff] * lds[L_XINL + ff];
                    cstore(&outBs[par * 128 + b_att * 8 + f], acc + outBias[f]);
                }
            }
            __syncthreads();
            if (tid < 16) {
                const int pp = tid >> 3, bb = tid & 7;
                ucstore(&h0cU[(par ^ 1) * 4096 + (half * 8 + bb) * 256 + j * 2 + pp],
                        packh2(lds[L_HS + (2 * pp) * 8 + bb], lds[L_HS + (2 * pp + 1) * 8 + bb]));
            }
            if (tid < 32)
                cstore(&hidPA[par * 8192 + b_att * 512 + sgrp * 32 + tid], 0.f);
        }
        bar_sync(halfCnt, 128 * (++bars));

        // ---- E: GRU1 x-side + gates; outP; hidP outer-product; zero weiA ----
        {
            if (tid < 16)  // FIXED layout: bb*2 + pp
                ldsU[L_H1OWN + (tid & 7) * 2 + (tid >> 3)] =
                    ucload(&h1cU[par * 4096 + (half * 8 + (tid & 7)) * 256 + j * 2 + (tid >> 3)]);
            uint4 a0, a1;
            ucl_e(a0, a1,
                  &h0cU[(par ^ 1) * 4096 + half * 2048 + tid * 4],
                  &h0cU[(par ^ 1) * 4096 + half * 2048 + (tid + 256) * 4]);
            {
                const int bb0i = tid >> 6, p40 = tid & 63;
                const int bb1i = (tid + 256) >> 6, p41 = (tid + 256) & 63;
                *(uint4*)&ldsU[L_S0 + bb0i * 264 + p40 * 4] = a0;
                *(uint4*)&ldsU[L_S0 + bb1i * 264 + p41 * 4] = a1;
            }
            __syncthreads();
            if (tid < 192) {
                const int u = tid >> 1, sub = tid & 1;
                const int bb = u & 7, gh = u >> 3;
                const int grow = (gh >> 2) * 512 + j * 4 + (gh & 3);
                const uint4* wx = (const uint4*)&wih1U[grow * 256 + sub * 128];
                const uint4* xp = (const uint4*)&ldsU[L_S0 + bb * 264 + sub * 128];
                float ax = 0.f;
#pragma unroll 8
                for (int k4 = 0; k4 < 32; ++k4) {
                    const uint4 xv = xp[k4], wv = wx[k4];
                    ax = dot2(xv.x, wv.x, ax); ax = dot2(xv.y, wv.y, ax);
                    ax = dot2(xv.z, wv.z, ax); ax = dot2(xv.w, wv.w, ax);
                }
                ax += __shfl_down(ax, 1, 2);
                if (sub == 0) lds[L_AX + gh * 8 + bb] = ax + lds[L_BIH1 + gh];
            }
            __syncthreads();
            if (tid < 32) {
                const int hr = tid >> 3, bb = tid & 7;
                const float r = fsig(lds[L_AX + hr * 8 + bb] + lds[L_AH1 + hr * 8 + bb]);
                const float z = fsig(lds[L_AX + (4 + hr) * 8 + bb] + lds[L_AH1 + (4 + hr) * 8 + bb]);
                const float n = ftanhf(lds[L_AX + (8 + hr) * 8 + bb] + r * lds[L_AH1 + (8 + hr) * 8 + bb]);
                U32H u; u.u = ldsU[L_H1OWN + bb * 2 + (hr >> 1)];
                const float hold = (hr & 1) ? (float)u.h.y : (float)u.h.x;
                lds[L_HS + hr * 8 + bb] = (1.f - z) * n + z * hold;
            }
            __syncthreads();
            if (tid < 16) {
                const int pp = tid >> 3, bb = tid & 7;
                ucstore(&h1cU[(par ^ 1) * 4096 + (half * 8 + bb) * 256 + j * 2 + pp],
                        packh2(lds[L_HS + (2 * pp) * 8 + bb], lds[L_HS + (2 * pp + 1) * 8 + bb]));
            }
            if (tid < 64) {
                const int f = tid >> 3, bb = tid & 7;
                float acc = 0.f;
#pragma unroll
                for (int hr = 0; hr < 4; ++hr)
                    acc += lds[L_OOW + f * 4 + hr] * lds[L_HS + hr * 8 + bb];
                cstore(&outP[((half * 8 + bb) * 128 + j) * 8 + f], acc);
            }
            {
                float wlo[4], whi[4];
#pragma unroll
                for (int k = 0; k < 4; ++k) {
                    U32H u; u.u = ldsU[L_WHIDT + k * 256 + tid];
                    wlo[k] = (float)u.h.x; whi[k] = (float)u.h.y;
                }
#pragma unroll
                for (int bb = 0; bb < 8; ++bb) {
                    float p0 = 0.f, p1 = 0.f;
#pragma unroll
                    for (int k = 0; k < 4; ++k) {
                        const float hv = lds[L_HS + k * 8 + bb];
                        p0 += hv * wlo[k]; p1 += hv * whi[k];
                    }
                    atomicAdd(&hidPA[(par ^ 1) * 8192 + (half * 8 + bb) * 512 + 2 * tid], p0);
                    atomicAdd(&hidPA[(par ^ 1) * 8192 + (half * 8 + bb) * 512 + 2 * tid + 1], p1);
                }
            }
            if (tid < 32) cstore(&weiA[par * 8192 + half * 4096 + j * 32 + tid], 0.f);
            if (sgrp == 0 && tid == 0) cstore(&lacc[par * 16 + b_att], 0.f);
        }
        bar_sync(halfCnt, 128 * (++bars));
    }

    // ---- epilogue: out[31] (par(31) = 1) ----
    if (sgrp == 15 && tid < 64) {
        const int f = tid >> 3, sub = tid & 7;
        float acc = 0.f;
        for (int i = 0; i < 16; ++i)
            acc += cload(&outP[(b_att * 128 + sub * 16 + i) * 8 + f]);
        acc += __shfl_down(acc, 4, 8); acc += __shfl_down(acc, 2, 8); acc += __shfl_down(acc, 1, 8);
        if (sub == 0) {
            acc += cload(&outBs[1 * 128 + b_att * 8 + f]);
            out[b_att * 256 + 31 * 8 + f] = fmaxf(acc, 0.f);
        }
    }
}

extern "C" void kernel_launch(void* const* d_in, const int* in_sizes, int n_in,
                              void* d_out, int out_size, void* d_ws, size_t ws_size,
                              hipStream_t stream) {
    (void)in_sizes; (void)n_in; (void)out_size; (void)ws_size;
    hipMemsetAsync(d_ws, 0, 4096, stream);  // zero barrier counters
    decoder_kernel<<<NBLK, NTHR, 0, stream>>>(
        (const float*)d_in[0], (const float*)d_in[1], (const float*)d_in[2],
        (const float*)d_in[3], (const float*)d_in[4], (const float*)d_in[5],
        (const float*)d_in[6], (const float*)d_in[7], (const float*)d_in[8],
        (const float*)d_in[9], (const float*)d_in[10], (const float*)d_in[11],
        (const float*)d_in[12], (const float*)d_in[13], (const float*)d_in[14],
        (const float*)d_in[15], (float*)d_out, (float*)d_ws);
}